// Round 14
// baseline (528.072 us; speedup 1.0000x reference)
//
#include <hip/hip_runtime.h>
#include <stdint.h>

#define NN 50000
#define NE 600000
#define DD 128
#define BN_EPS 1e-5f

typedef __attribute__((ext_vector_type(8))) short short8;
typedef __attribute__((ext_vector_type(4))) float f32x4;

__device__ __forceinline__ float bf2f(uint16_t u) {
    union { uint32_t u; float f; } v; v.u = ((uint32_t)u) << 16; return v.f;
}
__device__ __forceinline__ uint16_t f2bf(float f) {
    union { float f; uint32_t u; } v; v.f = f;
    return (uint16_t)((v.u + 0x7FFFu + ((v.u >> 16) & 1u)) >> 16);
}
__device__ __forceinline__ float lo16(uint32_t v) { return bf2f((uint16_t)(v & 0xFFFFu)); }
__device__ __forceinline__ float hi16(uint32_t v) { return bf2f((uint16_t)(v >> 16)); }

// ---------------- zero-init ----------------
__global__ void k_zero(uint4* __restrict__ p, int n16) {
    int i = blockIdx.x * 256 + threadIdx.x;
    if (i < n16) p[i] = make_uint4(0u, 0u, 0u, 0u);
}

// ---- fused: degree count [0,EB) || emb gather [EB,EB+VB) || W->bf16 cvt [.,+WB) ----
#define EB ((NE + 255) / 256)
#define VB ((NN * 32) / 256)
#define WB 32
#define NB ((NN + 255) / 256)
__global__ void k_pre(const int* __restrict__ ei, int* __restrict__ cnt,
                      const int* __restrict__ x_idx, const float* __restrict__ emb,
                      uint16_t* __restrict__ xb,
                      const float* __restrict__ Wa, const float* __restrict__ Wb_,
                      const float* __restrict__ Wc, const float* __restrict__ Wd,
                      uint16_t* __restrict__ wb) {
    int b = blockIdx.x;
    if (b < EB) {
        int e = b * 256 + threadIdx.x;
        if (e < NE) atomicAdd(&cnt[ei[NE + e]], 1);
    } else if (b < EB + VB) {
        int idx = (b - EB) * 256 + threadIdx.x;   // NN*32 threads, 4 elems each
        int node = idx >> 5, c4 = (idx & 31) << 2;
        int src = x_idx[node];
        float4 v = *(const float4*)(emb + (size_t)src * DD + c4);
        ushort4 o;
        o.x = f2bf(v.x); o.y = f2bf(v.y); o.z = f2bf(v.z); o.w = f2bf(v.w);
        *(ushort4*)(xb + (size_t)node * DD + c4) = o;
    } else {
        int idx = (b - EB - VB) * 256 + threadIdx.x;  // 8192 threads, 8 floats each
        int w = idx >> 11, rem = idx & 2047;
        const float* src = (w == 0) ? Wa : (w == 1) ? Wb_ : (w == 2) ? Wc : Wd;
        float4 v0 = *(const float4*)(src + rem * 8);
        float4 v1 = *(const float4*)(src + rem * 8 + 4);
        uint4 pk;
        pk.x = (uint32_t)f2bf(v0.x) | ((uint32_t)f2bf(v0.y) << 16);
        pk.y = (uint32_t)f2bf(v0.z) | ((uint32_t)f2bf(v0.w) << 16);
        pk.z = (uint32_t)f2bf(v1.x) | ((uint32_t)f2bf(v1.y) << 16);
        pk.w = (uint32_t)f2bf(v1.z) | ((uint32_t)f2bf(v1.w) << 16);
        int row = rem >> 4, c16 = rem & 15;
        uint32_t boff = (uint32_t)(row * 256 + ((c16 * 16) ^ ((row & 7) << 4)));
        *(uint4*)((char*)wb + (size_t)w * 32768 + boff) = pk;
    }
}

// ------- CSR alloc (wave-scan, 1 atomic/wave) + degree histogram -------
__global__ void k_alloc(const int* __restrict__ cnt, int* __restrict__ cursor,
                        int* __restrict__ off, int* __restrict__ fillp,
                        float* __restrict__ deginv, float* __restrict__ dis,
                        int* __restrict__ hist) {
    int i = blockIdx.x * 256 + threadIdx.x;
    int lane = threadIdx.x & 63;
    int deg = (i < NN) ? cnt[i] : 0;
    int v = deg;
    #pragma unroll
    for (int d = 1; d < 64; d <<= 1) {
        int t = __shfl_up(v, d, 64);
        if (lane >= d) v += t;
    }
    int total = __shfl(v, 63, 64);
    int wbase = 0;
    if (lane == 63) wbase = atomicAdd(cursor, total);
    wbase = __shfl(wbase, 63, 64);
    int base = wbase + v - deg;
    if (i < NN) {
        off[i] = base;
        fillp[i] = base;
        deginv[i] = 1.0f / fmaxf((float)deg, 1.0f);   // ClusterGCN 1/deg
        dis[i] = rsqrtf((float)deg + 1.0f);           // SGConv D^{-1/2} incl self-loop
        atomicAdd(&hist[min(deg, 511)], 1);
    }
}

// ------- exclusive scan of the 512-bucket degree histogram (1 block) -------
__global__ void k_hscan(int* __restrict__ hist) {
    __shared__ int s[512];
    int t = threadIdx.x;
    int v = hist[t];
    s[t] = v;
    __syncthreads();
    for (int d = 1; d < 512; d <<= 1) {
        int add = (t >= d) ? s[t - d] : 0;
        __syncthreads();
        s[t] += add;
        __syncthreads();
    }
    hist[t] = s[t] - v;  // exclusive base; consumed atomically by k_fill's perm pass
}

// ------- fused: CSR fill [0,EB) || degree-sort permutation [EB,EB+NB) -------
__global__ void k_fill(const int* __restrict__ ei, int* __restrict__ fillp,
                       int* __restrict__ csr_row, const int* __restrict__ cnt,
                       int* __restrict__ hist, int* __restrict__ perm) {
    int b = blockIdx.x;
    if (b < EB) {
        int e = b * 256 + threadIdx.x;
        if (e < NE) {
            int c = ei[NE + e];
            int p = atomicAdd(&fillp[c], 1);
            csr_row[p] = ei[e];
        }
    } else {
        int i = (b - EB) * 256 + threadIdx.x;
        if (i < NN) {
            int dg = min(cnt[i], 511);
            int sidx = atomicAdd(&hist[dg], 1);
            perm[sidx] = i;
        }
    }
}

// ------- aggregation: 1 wave = 4 degree-sorted nodes (16 lanes/node, uint4) -------
// perm groups equal-degree nodes -> minimal masked-slot waste in the shared loop.
template<int MODE>
__global__ __launch_bounds__(256)
void k_agg(const uint16_t* __restrict__ X, const int* __restrict__ off,
           const int* __restrict__ cnt, const int* __restrict__ csr_row,
           const int* __restrict__ perm,
           const float* __restrict__ deginv, const float* __restrict__ dis,
           uint16_t* __restrict__ aggb) {
    int gw = blockIdx.x * 4 + (threadIdx.x >> 6);
    int lane = threadIdx.x & 63;
    int ql = lane & 15;
    int slot = gw * 4 + (lane >> 4);
    if (slot >= NN) return;
    int node = perm[slot];
    float a0 = 0.0f, a1 = 0.0f, a2 = 0.0f, a3 = 0.0f;
    float a4 = 0.0f, a5 = 0.0f, a6 = 0.0f, a7 = 0.0f;
    if (MODE == 1) {
        uint4 v = ((const uint4*)(X + (size_t)node * DD))[ql];  // self term xs[n]
        a0 = lo16(v.x); a1 = hi16(v.x); a2 = lo16(v.y); a3 = hi16(v.y);
        a4 = lo16(v.z); a5 = hi16(v.z); a6 = lo16(v.w); a7 = hi16(v.w);
    }
    int s = off[node], deg = cnt[node];
    int m = max(deg, __shfl(deg, lane ^ 16, 64));
    m = max(m, __shfl(m, lane ^ 32, 64));           // max deg over the 4 quarters
    for (int b = 0; b < m; b += 16) {
        int c16 = min(deg - b, 16);                 // may be <= 0
        int idxv = (ql < c16) ? csr_row[s + b + ql] : 0;
        int steps = min(m - b, 16);
        int i = 0;
        for (; i + 8 <= steps; i += 8) {
            uint4 v[8]; float w[8];
            #pragma unroll
            for (int u = 0; u < 8; ++u) {
                int r = __shfl(idxv, (lane & 48) + i + u, 64);
                w[u] = (b + i + u < deg) ? 1.0f : 0.0f;
                v[u] = ((const uint4*)(X + (size_t)r * DD))[ql];
            }
            #pragma unroll
            for (int u = 0; u < 8; ++u) {
                a0 = fmaf(w[u], lo16(v[u].x), a0); a1 = fmaf(w[u], hi16(v[u].x), a1);
                a2 = fmaf(w[u], lo16(v[u].y), a2); a3 = fmaf(w[u], hi16(v[u].y), a3);
                a4 = fmaf(w[u], lo16(v[u].z), a4); a5 = fmaf(w[u], hi16(v[u].z), a5);
                a6 = fmaf(w[u], lo16(v[u].w), a6); a7 = fmaf(w[u], hi16(v[u].w), a7);
            }
        }
        if (i + 4 <= steps) {
            uint4 v[4]; float w[4];
            #pragma unroll
            for (int u = 0; u < 4; ++u) {
                int r = __shfl(idxv, (lane & 48) + i + u, 64);
                w[u] = (b + i + u < deg) ? 1.0f : 0.0f;
                v[u] = ((const uint4*)(X + (size_t)r * DD))[ql];
            }
            #pragma unroll
            for (int u = 0; u < 4; ++u) {
                a0 = fmaf(w[u], lo16(v[u].x), a0); a1 = fmaf(w[u], hi16(v[u].x), a1);
                a2 = fmaf(w[u], lo16(v[u].y), a2); a3 = fmaf(w[u], hi16(v[u].y), a3);
                a4 = fmaf(w[u], lo16(v[u].z), a4); a5 = fmaf(w[u], hi16(v[u].z), a5);
                a6 = fmaf(w[u], lo16(v[u].w), a6); a7 = fmaf(w[u], hi16(v[u].w), a7);
            }
            i += 4;
        }
        for (; i < steps; ++i) {
            int r = __shfl(idxv, (lane & 48) + i, 64);
            float w = (b + i < deg) ? 1.0f : 0.0f;
            uint4 v = ((const uint4*)(X + (size_t)r * DD))[ql];
            a0 = fmaf(w, lo16(v.x), a0); a1 = fmaf(w, hi16(v.x), a1);
            a2 = fmaf(w, lo16(v.y), a2); a3 = fmaf(w, hi16(v.y), a3);
            a4 = fmaf(w, lo16(v.z), a4); a5 = fmaf(w, hi16(v.z), a5);
            a6 = fmaf(w, lo16(v.w), a6); a7 = fmaf(w, hi16(v.w), a7);
        }
    }
    float sc = (MODE == 1) ? dis[node] : deginv[node];
    a0 *= sc; a1 *= sc; a2 *= sc; a3 *= sc;
    a4 *= sc; a5 *= sc; a6 *= sc; a7 *= sc;
    uint4 o;
    o.x = (uint32_t)f2bf(a0) | ((uint32_t)f2bf(a1) << 16);
    o.y = (uint32_t)f2bf(a2) | ((uint32_t)f2bf(a3) << 16);
    o.z = (uint32_t)f2bf(a4) | ((uint32_t)f2bf(a5) << 16);
    o.w = (uint32_t)f2bf(a6) | ((uint32_t)f2bf(a7) << 16);
    ((uint4*)(aggb + (size_t)node * DD))[ql] = o;
}

// ------------- MFMA GEMM: A prefetch to regs; W staged via global_load_lds -------------
template<bool DUAL, bool STATS, bool BIAS, bool STORE_BF16>
__global__ __launch_bounds__(256, DUAL ? 2 : 3)
void k_gemm(const uint16_t* __restrict__ A1, const uint16_t* __restrict__ A2,
            const uint16_t* __restrict__ Wb1, const uint16_t* __restrict__ Wb2,
            const float* __restrict__ bias, float* __restrict__ Hf,
            uint16_t* __restrict__ Hb, float* __restrict__ stats) {
    constexpr int NW = DUAL ? 2 : 1;
    __shared__ uint16_t Wlds[NW * 128 * 128];
    const int t = threadIdx.x;
    const int lane = t & 63, wid = t >> 6;
    const int l15 = lane & 15, kgrp = lane >> 4;
    const int wm = (wid >> 1) * 64, wn = (wid & 1) * 64;
    const int m0 = blockIdx.x * 128;

    // 1) stage W tile(s): linear async copy (source pre-swizzled)
    #pragma unroll
    for (int w = 0; w < NW; ++w) {
        const char* Ws = (const char*)(w ? Wb2 : Wb1);
        char* ldsb = (char*)Wlds + w * 32768;
        #pragma unroll
        for (int it = 0; it < 8; ++it) {
            int base_chunk = it * 256 + (t & 192);   // wave-uniform (wid*64)
            int lane_chunk = base_chunk + (t & 63);
            __builtin_amdgcn_global_load_lds(
                (const __attribute__((address_space(1))) uint32_t*)(Ws + (size_t)lane_chunk * 16),
                (__attribute__((address_space(3))) uint32_t*)(uint32_t)(uintptr_t)(ldsb + base_chunk * 16),
                16, 0, 0);
        }
    }
    // 2) prefetch A1 tile fragments (latency overlaps the W DMA)
    short8 a1r[4][4];
    #pragma unroll
    for (int m = 0; m < 4; ++m) {
        int row = min(m0 + wm + m * 16 + l15, NN - 1);
        const uint16_t* ap = A1 + (size_t)row * DD + kgrp * 8;
        #pragma unroll
        for (int ks = 0; ks < 4; ++ks)
            a1r[m][ks] = *(const short8*)(ap + ks * 32);
    }
    __syncthreads();

    f32x4 acc[4][4];
    #pragma unroll
    for (int m = 0; m < 4; ++m)
        #pragma unroll
        for (int n = 0; n < 4; ++n) acc[m][n] = f32x4{0.0f, 0.0f, 0.0f, 0.0f};

    // 3) DUAL: issue A2 prefetch now; hides under phase-0 MFMAs
    short8 a2r[4][4];
    if (DUAL) {
        #pragma unroll
        for (int m = 0; m < 4; ++m) {
            int row = min(m0 + wm + m * 16 + l15, NN - 1);
            const uint16_t* ap = A2 + (size_t)row * DD + kgrp * 8;
            #pragma unroll
            for (int ks = 0; ks < 4; ++ks)
                a2r[m][ks] = *(const short8*)(ap + ks * 32);
        }
    }
    // 4) MFMA phases
    #pragma unroll
    for (int ph = 0; ph < NW; ++ph) {
        #pragma unroll
        for (int ks = 0; ks < 4; ++ks) {
            short8 b[4];
            int kb = ks * 64 + (kgrp << 4);
            #pragma unroll
            for (int n = 0; n < 4; ++n) {
                int row = wn + n * 16 + l15;
                b[n] = *(const short8*)((const char*)Wlds + ph * 32768
                                        + row * 256 + (kb ^ ((row & 7) << 4)));
            }
            #pragma unroll
            for (int m = 0; m < 4; ++m)
                #pragma unroll
                for (int n = 0; n < 4; ++n)
                    acc[m][n] = __builtin_amdgcn_mfma_f32_16x16x32_bf16(
                        (ph ? a2r : a1r)[m][ks], b[n], acc[m][n], 0, 0, 0);
        }
    }
    // epilogue: bias, store, per-channel stats into copy (wid | blockparity)
    float* stc = STATS ? stats + ((wid + ((blockIdx.x & 1) << 2)) & 7) * 256 : nullptr;
    #pragma unroll
    for (int n = 0; n < 4; ++n) {
        int col = wn + n * 16 + l15;
        float bb = BIAS ? bias[col] : 0.0f;
        float ssum = 0.0f, ssq = 0.0f;
        #pragma unroll
        for (int m = 0; m < 4; ++m) {
            int rbase = m0 + wm + m * 16 + kgrp * 4;
            #pragma unroll
            for (int i = 0; i < 4; ++i) {
                int gr = rbase + i;
                if (gr < NN) {
                    float v = acc[m][n][i] + bb;
                    if (STORE_BF16) Hb[(size_t)gr * DD + col] = f2bf(v);
                    else            Hf[(size_t)gr * DD + col] = v;
                    ssum += v; ssq += v * v;
                }
            }
        }
        if (STATS) {
            ssum += __shfl_xor(ssum, 16, 64);
            ssum += __shfl_xor(ssum, 32, 64);
            ssq  += __shfl_xor(ssq, 16, 64);
            ssq  += __shfl_xor(ssq, 32, 64);
            if (lane < 16) {
                atomicAdd(&stc[col], ssum);
                atomicAdd(&stc[128 + col], ssq);
            }
        }
    }
}

// ---------------- fused BN prep + apply + ReLU + dis pre-scale ----------------
// stats layout: 8 copies x (128 sum + 128 sumsq)
__global__ __launch_bounds__(256)
void k_bnrelu(const uint16_t* __restrict__ Hb, const float* __restrict__ st,
              const float* __restrict__ gamma, const float* __restrict__ beta,
              const float* __restrict__ dis, uint16_t* __restrict__ xb) {
    __shared__ float s_sc[128], s_of[128];
    int t = threadIdx.x;
    if (t < 128) {
        const float invn = 1.0f / (float)NN;
        float sum = 0.0f, sq = 0.0f;
        #pragma unroll
        for (int k = 0; k < 8; ++k) {
            sum += st[k * 256 + t];
            sq  += st[k * 256 + 128 + t];
        }
        float mean = sum * invn;
        float var = sq * invn - mean * mean;
        float sc = gamma[t] * rsqrtf(var + BN_EPS);
        s_sc[t] = sc;
        s_of[t] = beta[t] - mean * sc;
    }
    __syncthreads();
    int idx = blockIdx.x * 256 + t;              // 16 threads/row, 8 elems/thread
    int node = idx >> 4, c8 = (idx & 15) << 3;
    if (node >= NN) return;
    float d = dis[node];
    uint4 h = *(const uint4*)(Hb + (size_t)node * DD + c8);
    uint32_t hw[4] = {h.x, h.y, h.z, h.w};
    uint32_t ow[4];
    #pragma unroll
    for (int j = 0; j < 4; ++j) {
        int c = c8 + j * 2;
        float v0 = fmaxf(lo16(hw[j]) * s_sc[c]     + s_of[c],     0.0f) * d;
        float v1 = fmaxf(hi16(hw[j]) * s_sc[c + 1] + s_of[c + 1], 0.0f) * d;
        ow[j] = (uint32_t)f2bf(v0) | ((uint32_t)f2bf(v1) << 16);
    }
    uint4 o = make_uint4(ow[0], ow[1], ow[2], ow[3]);
    *(uint4*)(xb + (size_t)node * DD + c8) = o;
}

// ---------------- launch ----------------
extern "C" void kernel_launch(void* const* d_in, const int* in_sizes, int n_in,
                              void* d_out, int out_size, void* d_ws, size_t ws_size,
                              hipStream_t stream) {
    const int* x_idx   = (const int*)d_in[0];
    const int* ei      = (const int*)d_in[1];
    const float* emb   = (const float*)d_in[2];
    const float* W_out = (const float*)d_in[3];
    const float* W_root= (const float*)d_in[4];
    const float* g0    = (const float*)d_in[5];
    const float* be0   = (const float*)d_in[6];
    const float* W1    = (const float*)d_in[7];
    const float* b1    = (const float*)d_in[8];
    const float* g1    = (const float*)d_in[9];
    const float* be1   = (const float*)d_in[10];
    const float* W2    = (const float*)d_in[11];
    const float* b2    = (const float*)d_in[12];
    float* out = (float*)d_out;

    char* ws = (char*)d_ws;
    size_t o = 0;
    auto carve = [&](size_t bytes) -> void* {
        void* p = ws + o;
        o = (o + bytes + 255) & ~(size_t)255;
        return p;
    };
    // zero-init group first (single k_zero pass)
    int* cnt      = (int*)carve((size_t)NN * 4);
    int* cursor   = (int*)carve(4);
    float* st0    = (float*)carve(2048 * 4);     // 8 copies x (sum|sumsq)
    float* st1    = (float*)carve(2048 * 4);
    int* hist     = (int*)carve(512 * 4);
    size_t zlen = o;                             // multiple of 256
    // rest
    int* fillp    = (int*)carve((size_t)NN * 4);
    int* off      = (int*)carve((size_t)NN * 4);
    float* deginv = (float*)carve((size_t)NN * 4);
    float* dis    = (float*)carve((size_t)NN * 4);
    int* csr_row  = (int*)carve((size_t)NE * 4);
    int* perm     = (int*)carve((size_t)NN * 4);
    uint16_t* xb  = (uint16_t*)carve((size_t)NN * DD * 2);
    uint16_t* aggb= (uint16_t*)carve((size_t)NN * DD * 2);
    uint16_t* hb  = (uint16_t*)carve((size_t)NN * DD * 2);
    uint16_t* wb  = (uint16_t*)carve((size_t)4 * 16384 * 2);  // 4 pre-swizzled bf16 W blobs

    const int ZB = (int)((zlen / 16 + 255) / 256);
    const int GB = (NN + 127) / 128;            // 391 GEMM tiles
    const int AB = (NN + 15) / 16;              // 3125 agg blocks (4 nodes/wave)
    const int BB = (NN * 16 + 255) / 256;       // 3125 bnrelu blocks

    k_zero<<<ZB, 256, 0, stream>>>((uint4*)ws, (int)(zlen / 16));
    k_pre<<<EB + VB + WB, 256, 0, stream>>>(ei, cnt, x_idx, emb, xb,
                                            W_out, W_root, W1, W2, wb);
    k_alloc<<<NB, 256, 0, stream>>>(cnt, cursor, off, fillp, deginv, dis, hist);
    k_hscan<<<1, 512, 0, stream>>>(hist);
    k_fill<<<EB + NB, 256, 0, stream>>>(ei, fillp, csr_row, cnt, hist, perm);

    // layer 0: ClusterGCN -> GEMM(dual, +stats) -> bnrelu
    k_agg<0><<<AB, 256, 0, stream>>>(xb, off, cnt, csr_row, perm, deginv, dis, aggb);
    k_gemm<true, true, false, true><<<GB, 256, 0, stream>>>(
        aggb, xb, wb, wb + 16384, nullptr, nullptr, hb, st0);
    k_bnrelu<<<BB, 256, 0, stream>>>(hb, st0, g0, be0, dis, xb);

    // layer 1: SGConv -> GEMM(+stats) -> bnrelu
    k_agg<1><<<AB, 256, 0, stream>>>(xb, off, cnt, csr_row, perm, deginv, dis, aggb);
    k_gemm<false, true, true, true><<<GB, 256, 0, stream>>>(
        aggb, nullptr, wb + 32768, nullptr, b1, nullptr, hb, st1);
    k_bnrelu<<<BB, 256, 0, stream>>>(hb, st1, g1, be1, dis, xb);

    // layer 2: final SGConv -> GEMM -> d_out (fp32)
    k_agg<1><<<AB, 256, 0, stream>>>(xb, off, cnt, csr_row, perm, deginv, dis, aggb);
    k_gemm<false, false, true, false><<<GB, 256, 0, stream>>>(
        aggb, nullptr, wb + 49152, nullptr, b2, out, nullptr, nullptr);
}

// Round 15
// 221.470 us; speedup vs baseline: 2.3844x; 2.3844x over previous
//
#include <hip/hip_runtime.h>
#include <stdint.h>

#define NN 50000
#define NE 600000
#define DD 128
#define BN_EPS 1e-5f

typedef __attribute__((ext_vector_type(8))) short short8;
typedef __attribute__((ext_vector_type(4))) float f32x4;

__device__ __forceinline__ float bf2f(uint16_t u) {
    union { uint32_t u; float f; } v; v.u = ((uint32_t)u) << 16; return v.f;
}
__device__ __forceinline__ uint16_t f2bf(float f) {
    union { float f; uint32_t u; } v; v.f = f;
    return (uint16_t)((v.u + 0x7FFFu + ((v.u >> 16) & 1u)) >> 16);
}
__device__ __forceinline__ float lo16(uint32_t v) { return bf2f((uint16_t)(v & 0xFFFFu)); }
__device__ __forceinline__ float hi16(uint32_t v) { return bf2f((uint16_t)(v >> 16)); }

// ---------------- zero-init ----------------
__global__ void k_zero(uint4* __restrict__ p, int n16) {
    int i = blockIdx.x * 256 + threadIdx.x;
    if (i < n16) p[i] = make_uint4(0u, 0u, 0u, 0u);
}

// ---- fused: degree count [0,EB) || emb gather [EB,EB+VB) || W->bf16 cvt [.,+WB) ----
// W is written PRE-SWIZZLED (same XOR formula the GEMM reads with) so the GEMM
// can stage it with linear global_load_lds (m173 pattern: swizzle source, LDS linear).
#define EB ((NE + 255) / 256)
#define VB ((NN * 32) / 256)
#define WB 32
__global__ void k_pre(const int* __restrict__ ei, int* __restrict__ cnt,
                      const int* __restrict__ x_idx, const float* __restrict__ emb,
                      uint16_t* __restrict__ xb,
                      const float* __restrict__ Wa, const float* __restrict__ Wb_,
                      const float* __restrict__ Wc, const float* __restrict__ Wd,
                      uint16_t* __restrict__ wb) {
    int b = blockIdx.x;
    if (b < EB) {
        int e = b * 256 + threadIdx.x;
        if (e < NE) atomicAdd(&cnt[ei[NE + e]], 1);
    } else if (b < EB + VB) {
        int idx = (b - EB) * 256 + threadIdx.x;   // NN*32 threads, 4 elems each
        int node = idx >> 5, c4 = (idx & 31) << 2;
        int src = x_idx[node];
        float4 v = *(const float4*)(emb + (size_t)src * DD + c4);
        ushort4 o;
        o.x = f2bf(v.x); o.y = f2bf(v.y); o.z = f2bf(v.z); o.w = f2bf(v.w);
        *(ushort4*)(xb + (size_t)node * DD + c4) = o;
    } else {
        int idx = (b - EB - VB) * 256 + threadIdx.x;  // 8192 threads, 8 floats each
        int w = idx >> 11, rem = idx & 2047;
        const float* src = (w == 0) ? Wa : (w == 1) ? Wb_ : (w == 2) ? Wc : Wd;
        float4 v0 = *(const float4*)(src + rem * 8);
        float4 v1 = *(const float4*)(src + rem * 8 + 4);
        uint4 pk;
        pk.x = (uint32_t)f2bf(v0.x) | ((uint32_t)f2bf(v0.y) << 16);
        pk.y = (uint32_t)f2bf(v0.z) | ((uint32_t)f2bf(v0.w) << 16);
        pk.z = (uint32_t)f2bf(v1.x) | ((uint32_t)f2bf(v1.y) << 16);
        pk.w = (uint32_t)f2bf(v1.z) | ((uint32_t)f2bf(v1.w) << 16);
        int row = rem >> 4, c16 = rem & 15;
        uint32_t boff = (uint32_t)(row * 256 + ((c16 * 16) ^ ((row & 7) << 4)));
        *(uint4*)((char*)wb + (size_t)w * 32768 + boff) = pk;
    }
}

// ---------------- CSR alloc (wave-scan, 1 atomic/wave) + fill ----------------
__global__ void k_alloc(const int* __restrict__ cnt, int* __restrict__ cursor,
                        int* __restrict__ off, int* __restrict__ fillp,
                        float* __restrict__ deginv, float* __restrict__ dis) {
    int i = blockIdx.x * 256 + threadIdx.x;
    int lane = threadIdx.x & 63;
    int deg = (i < NN) ? cnt[i] : 0;
    int v = deg;
    #pragma unroll
    for (int d = 1; d < 64; d <<= 1) {
        int t = __shfl_up(v, d, 64);
        if (lane >= d) v += t;
    }
    int total = __shfl(v, 63, 64);
    int wbase = 0;
    if (lane == 63) wbase = atomicAdd(cursor, total);
    wbase = __shfl(wbase, 63, 64);
    int base = wbase + v - deg;
    if (i < NN) {
        off[i] = base;
        fillp[i] = base;
        deginv[i] = 1.0f / fmaxf((float)deg, 1.0f);   // ClusterGCN 1/deg
        dis[i] = rsqrtf((float)deg + 1.0f);           // SGConv D^{-1/2} incl self-loop
    }
}

__global__ void k_fill(const int* __restrict__ ei, int* __restrict__ fillp,
                       int* __restrict__ csr_row) {
    int e = blockIdx.x * 256 + threadIdx.x;
    if (e < NE) {
        int c = ei[NE + e];
        int p = atomicAdd(&fillp[c], 1);
        csr_row[p] = ei[e];
    }
}

// ------------- aggregation: 1 wave = 2 nodes (32 lanes/node, uint2 = 4 ch/lane) -------------
template<int MODE>
__global__ __launch_bounds__(256)
void k_agg(const uint16_t* __restrict__ X, const int* __restrict__ off,
           const int* __restrict__ cnt, const int* __restrict__ csr_row,
           const float* __restrict__ deginv, const float* __restrict__ dis,
           uint16_t* __restrict__ aggb) {
    int gw = blockIdx.x * 4 + (threadIdx.x >> 6);
    int lane = threadIdx.x & 63;
    int hl = lane & 31;
    int node = gw * 2 + (lane >> 5);
    if (node >= NN) return;
    float a0 = 0.0f, a1 = 0.0f, a2 = 0.0f, a3 = 0.0f;
    if (MODE == 1) {
        uint2 v = ((const uint2*)(X + (size_t)node * DD))[hl];  // self term xs[n]
        a0 = lo16(v.x); a1 = hi16(v.x); a2 = lo16(v.y); a3 = hi16(v.y);
    }
    int s = off[node], deg = cnt[node];
    int degO = __shfl(deg, lane ^ 32, 64);
    int mdeg = max(deg, degO);
    for (int b = 0; b < mdeg; b += 32) {
        int c32 = min(deg - b, 32);
        int idxv = (hl < c32) ? csr_row[s + b + hl] : 0;
        int steps = min(mdeg - b, 32);
        int i = 0;
        for (; i + 8 <= steps; i += 8) {
            uint2 v[8]; float w[8];
            #pragma unroll
            for (int u = 0; u < 8; ++u) {
                int r = __shfl(idxv, (lane & 32) + i + u, 64);
                w[u] = (b + i + u < deg) ? 1.0f : 0.0f;
                v[u] = ((const uint2*)(X + (size_t)r * DD))[hl];
            }
            #pragma unroll
            for (int u = 0; u < 8; ++u) {
                a0 = fmaf(w[u], lo16(v[u].x), a0);
                a1 = fmaf(w[u], hi16(v[u].x), a1);
                a2 = fmaf(w[u], lo16(v[u].y), a2);
                a3 = fmaf(w[u], hi16(v[u].y), a3);
            }
        }
        if (i + 4 <= steps) {
            uint2 v[4]; float w[4];
            #pragma unroll
            for (int u = 0; u < 4; ++u) {
                int r = __shfl(idxv, (lane & 32) + i + u, 64);
                w[u] = (b + i + u < deg) ? 1.0f : 0.0f;
                v[u] = ((const uint2*)(X + (size_t)r * DD))[hl];
            }
            #pragma unroll
            for (int u = 0; u < 4; ++u) {
                a0 = fmaf(w[u], lo16(v[u].x), a0);
                a1 = fmaf(w[u], hi16(v[u].x), a1);
                a2 = fmaf(w[u], lo16(v[u].y), a2);
                a3 = fmaf(w[u], hi16(v[u].y), a3);
            }
            i += 4;
        }
        for (; i < steps; ++i) {
            int r = __shfl(idxv, (lane & 32) + i, 64);
            float w = (b + i < deg) ? 1.0f : 0.0f;
            uint2 v = ((const uint2*)(X + (size_t)r * DD))[hl];
            a0 = fmaf(w, lo16(v.x), a0);
            a1 = fmaf(w, hi16(v.x), a1);
            a2 = fmaf(w, lo16(v.y), a2);
            a3 = fmaf(w, hi16(v.y), a3);
        }
    }
    float sc = (MODE == 1) ? dis[node] : deginv[node];
    a0 *= sc; a1 *= sc; a2 *= sc; a3 *= sc;
    uint2 o;
    o.x = (uint32_t)f2bf(a0) | ((uint32_t)f2bf(a1) << 16);
    o.y = (uint32_t)f2bf(a2) | ((uint32_t)f2bf(a3) << 16);
    ((uint2*)(aggb + (size_t)node * DD))[hl] = o;
}

// ------------- MFMA GEMM: A prefetch to regs; W staged via global_load_lds -------------
// W source is pre-swizzled in k_pre -> linear LDS copy, swizzled read (m173 pattern).
// 128x128 tile/block, 4 waves in 2x2 of 64x64. Stats into 8 interleaved copies.
template<bool DUAL, bool STATS, bool BIAS, bool STORE_BF16>
__global__ __launch_bounds__(256, DUAL ? 2 : 3)
void k_gemm(const uint16_t* __restrict__ A1, const uint16_t* __restrict__ A2,
            const uint16_t* __restrict__ Wb1, const uint16_t* __restrict__ Wb2,
            const float* __restrict__ bias, float* __restrict__ Hf,
            uint16_t* __restrict__ Hb, float* __restrict__ stats) {
    constexpr int NW = DUAL ? 2 : 1;
    __shared__ uint16_t Wlds[NW * 128 * 128];
    const int t = threadIdx.x;
    const int lane = t & 63, wid = t >> 6;
    const int l15 = lane & 15, kgrp = lane >> 4;
    const int wm = (wid >> 1) * 64, wn = (wid & 1) * 64;
    const int m0 = blockIdx.x * 128;

    // 1) stage W tile(s): linear async copy (source pre-swizzled)
    #pragma unroll
    for (int w = 0; w < NW; ++w) {
        const char* Ws = (const char*)(w ? Wb2 : Wb1);
        char* ldsb = (char*)Wlds + w * 32768;
        #pragma unroll
        for (int it = 0; it < 8; ++it) {
            int base_chunk = it * 256 + (t & 192);   // wave-uniform (wid*64)
            int lane_chunk = base_chunk + (t & 63);
            __builtin_amdgcn_global_load_lds(
                (const __attribute__((address_space(1))) uint32_t*)(Ws + (size_t)lane_chunk * 16),
                (__attribute__((address_space(3))) uint32_t*)(uint32_t)(uintptr_t)(ldsb + base_chunk * 16),
                16, 0, 0);
        }
    }
    // 2) prefetch A1 tile fragments (latency overlaps the W DMA)
    short8 a1r[4][4];
    #pragma unroll
    for (int m = 0; m < 4; ++m) {
        int row = min(m0 + wm + m * 16 + l15, NN - 1);
        const uint16_t* ap = A1 + (size_t)row * DD + kgrp * 8;
        #pragma unroll
        for (int ks = 0; ks < 4; ++ks)
            a1r[m][ks] = *(const short8*)(ap + ks * 32);
    }
    __syncthreads();

    f32x4 acc[4][4];
    #pragma unroll
    for (int m = 0; m < 4; ++m)
        #pragma unroll
        for (int n = 0; n < 4; ++n) acc[m][n] = f32x4{0.0f, 0.0f, 0.0f, 0.0f};

    // 3) DUAL: issue A2 prefetch now; hides under phase-0 MFMAs
    short8 a2r[4][4];
    if (DUAL) {
        #pragma unroll
        for (int m = 0; m < 4; ++m) {
            int row = min(m0 + wm + m * 16 + l15, NN - 1);
            const uint16_t* ap = A2 + (size_t)row * DD + kgrp * 8;
            #pragma unroll
            for (int ks = 0; ks < 4; ++ks)
                a2r[m][ks] = *(const short8*)(ap + ks * 32);
        }
    }
    // 4) MFMA phases
    #pragma unroll
    for (int ph = 0; ph < NW; ++ph) {
        #pragma unroll
        for (int ks = 0; ks < 4; ++ks) {
            short8 b[4];
            int kb = ks * 64 + (kgrp << 4);
            #pragma unroll
            for (int n = 0; n < 4; ++n) {
                int row = wn + n * 16 + l15;
                b[n] = *(const short8*)((const char*)Wlds + ph * 32768
                                        + row * 256 + (kb ^ ((row & 7) << 4)));
            }
            #pragma unroll
            for (int m = 0; m < 4; ++m)
                #pragma unroll
                for (int n = 0; n < 4; ++n)
                    acc[m][n] = __builtin_amdgcn_mfma_f32_16x16x32_bf16(
                        (ph ? a2r : a1r)[m][ks], b[n], acc[m][n], 0, 0, 0);
        }
    }
    // epilogue: bias, store, per-channel stats into copy (wid | blockparity)
    float* stc = STATS ? stats + ((wid + ((blockIdx.x & 1) << 2)) & 7) * 256 : nullptr;
    #pragma unroll
    for (int n = 0; n < 4; ++n) {
        int col = wn + n * 16 + l15;
        float bb = BIAS ? bias[col] : 0.0f;
        float ssum = 0.0f, ssq = 0.0f;
        #pragma unroll
        for (int m = 0; m < 4; ++m) {
            int rbase = m0 + wm + m * 16 + kgrp * 4;
            #pragma unroll
            for (int i = 0; i < 4; ++i) {
                int gr = rbase + i;
                if (gr < NN) {
                    float v = acc[m][n][i] + bb;
                    if (STORE_BF16) Hb[(size_t)gr * DD + col] = f2bf(v);
                    else            Hf[(size_t)gr * DD + col] = v;
                    ssum += v; ssq += v * v;
                }
            }
        }
        if (STATS) {
            ssum += __shfl_xor(ssum, 16, 64);
            ssum += __shfl_xor(ssum, 32, 64);
            ssq  += __shfl_xor(ssq, 16, 64);
            ssq  += __shfl_xor(ssq, 32, 64);
            if (lane < 16) {
                atomicAdd(&stc[col], ssum);
                atomicAdd(&stc[128 + col], ssq);
            }
        }
    }
}

// ---------------- fused BN prep + apply + ReLU + dis pre-scale ----------------
// stats layout: 8 copies x (128 sum + 128 sumsq)
__global__ __launch_bounds__(256)
void k_bnrelu(const uint16_t* __restrict__ Hb, const float* __restrict__ st,
              const float* __restrict__ gamma, const float* __restrict__ beta,
              const float* __restrict__ dis, uint16_t* __restrict__ xb) {
    __shared__ float s_sc[128], s_of[128];
    int t = threadIdx.x;
    if (t < 128) {
        const float invn = 1.0f / (float)NN;
        float sum = 0.0f, sq = 0.0f;
        #pragma unroll
        for (int k = 0; k < 8; ++k) {
            sum += st[k * 256 + t];
            sq  += st[k * 256 + 128 + t];
        }
        float mean = sum * invn;
        float var = sq * invn - mean * mean;
        float sc = gamma[t] * rsqrtf(var + BN_EPS);
        s_sc[t] = sc;
        s_of[t] = beta[t] - mean * sc;
    }
    __syncthreads();
    int idx = blockIdx.x * 256 + t;              // 16 threads/row, 8 elems/thread
    int node = idx >> 4, c8 = (idx & 15) << 3;
    if (node >= NN) return;
    float d = dis[node];
    uint4 h = *(const uint4*)(Hb + (size_t)node * DD + c8);
    uint32_t hw[4] = {h.x, h.y, h.z, h.w};
    uint32_t ow[4];
    #pragma unroll
    for (int j = 0; j < 4; ++j) {
        int c = c8 + j * 2;
        float v0 = fmaxf(lo16(hw[j]) * s_sc[c]     + s_of[c],     0.0f) * d;
        float v1 = fmaxf(hi16(hw[j]) * s_sc[c + 1] + s_of[c + 1], 0.0f) * d;
        ow[j] = (uint32_t)f2bf(v0) | ((uint32_t)f2bf(v1) << 16);
    }
    uint4 o = make_uint4(ow[0], ow[1], ow[2], ow[3]);
    *(uint4*)(xb + (size_t)node * DD + c8) = o;
}

// ---------------- launch ----------------
extern "C" void kernel_launch(void* const* d_in, const int* in_sizes, int n_in,
                              void* d_out, int out_size, void* d_ws, size_t ws_size,
                              hipStream_t stream) {
    const int* x_idx   = (const int*)d_in[0];
    const int* ei      = (const int*)d_in[1];
    const float* emb   = (const float*)d_in[2];
    const float* W_out = (const float*)d_in[3];
    const float* W_root= (const float*)d_in[4];
    const float* g0    = (const float*)d_in[5];
    const float* be0   = (const float*)d_in[6];
    const float* W1    = (const float*)d_in[7];
    const float* b1    = (const float*)d_in[8];
    const float* g1    = (const float*)d_in[9];
    const float* be1   = (const float*)d_in[10];
    const float* W2    = (const float*)d_in[11];
    const float* b2    = (const float*)d_in[12];
    float* out = (float*)d_out;

    char* ws = (char*)d_ws;
    size_t o = 0;
    auto carve = [&](size_t bytes) -> void* {
        void* p = ws + o;
        o = (o + bytes + 255) & ~(size_t)255;
        return p;
    };
    // zero-init group first (single k_zero pass)
    int* cnt      = (int*)carve((size_t)NN * 4);
    int* cursor   = (int*)carve(4);
    float* st0    = (float*)carve(2048 * 4);     // 8 copies x (sum|sumsq)
    float* st1    = (float*)carve(2048 * 4);
    size_t zlen = o;                             // multiple of 256
    // rest
    int* fillp    = (int*)carve((size_t)NN * 4);
    int* off      = (int*)carve((size_t)NN * 4);
    float* deginv = (float*)carve((size_t)NN * 4);
    float* dis    = (float*)carve((size_t)NN * 4);
    int* csr_row  = (int*)carve((size_t)NE * 4);
    uint16_t* xb  = (uint16_t*)carve((size_t)NN * DD * 2);
    uint16_t* aggb= (uint16_t*)carve((size_t)NN * DD * 2);
    uint16_t* hb  = (uint16_t*)carve((size_t)NN * DD * 2);
    uint16_t* wb  = (uint16_t*)carve((size_t)4 * 16384 * 2);  // 4 pre-swizzled bf16 W blobs

    const int ZB = (int)((zlen / 16 + 255) / 256);
    const int NB = (NN + 255) / 256;            // 196
    const int GB = (NN + 127) / 128;            // 391 GEMM tiles
    const int AB = (NN / 2 + 3) / 4;            // 6250 agg blocks (2 nodes/wave)
    const int BB = (NN * 16 + 255) / 256;       // 3125 bnrelu blocks

    k_zero<<<ZB, 256, 0, stream>>>((uint4*)ws, (int)(zlen / 16));
    k_pre<<<EB + VB + WB, 256, 0, stream>>>(ei, cnt, x_idx, emb, xb,
                                            W_out, W_root, W1, W2, wb);
    k_alloc<<<NB, 256, 0, stream>>>(cnt, cursor, off, fillp, deginv, dis);
    k_fill<<<EB, 256, 0, stream>>>(ei, fillp, csr_row);

    // layer 0: ClusterGCN -> GEMM(dual, +stats) -> bnrelu
    k_agg<0><<<AB, 256, 0, stream>>>(xb, off, cnt, csr_row, deginv, dis, aggb);
    k_gemm<true, true, false, true><<<GB, 256, 0, stream>>>(
        aggb, xb, wb, wb + 16384, nullptr, nullptr, hb, st0);
    k_bnrelu<<<BB, 256, 0, stream>>>(hb, st0, g0, be0, dis, xb);

    // layer 1: SGConv -> GEMM(+stats) -> bnrelu
    k_agg<1><<<AB, 256, 0, stream>>>(xb, off, cnt, csr_row, deginv, dis, aggb);
    k_gemm<false, true, true, true><<<GB, 256, 0, stream>>>(
        aggb, nullptr, wb + 32768, nullptr, b1, nullptr, hb, st1);
    k_bnrelu<<<BB, 256, 0, stream>>>(hb, st1, g1, be1, dis, xb);

    // layer 2: final SGConv -> GEMM -> d_out (fp32)
    k_agg<1><<<AB, 256, 0, stream>>>(xb, off, cnt, csr_row, deginv, dis, aggb);
    k_gemm<false, false, true, false><<<GB, 256, 0, stream>>>(
        aggb, nullptr, wb + 49152, nullptr, b2, out, nullptr, nullptr);
}